// Round 14
// baseline (171.514 us; speedup 1.0000x reference)
//
#include <hip/hip_runtime.h>
#include <hip/hip_bf16.h>

// Problem constants
constexpr int Bc  = 2;
constexpr int Sq  = 1024;   // query seq len
constexpr int CTX = 1024;
constexpr int Tt  = 2048;   // total kv len
constexpr int HID = 2048;
constexpr int NH  = 32;
constexpr int NKV = 8;
constexpr int HD  = 64;

typedef __bf16 bf16_t;
typedef bf16_t bf16x8 __attribute__((ext_vector_type(8)));
typedef bf16_t bf16x4 __attribute__((ext_vector_type(4)));
typedef bf16_t bf16x2 __attribute__((ext_vector_type(2)));
typedef float  f32x4  __attribute__((ext_vector_type(4)));
typedef short  s16x4  __attribute__((ext_vector_type(4)));
typedef short  s16x8  __attribute__((ext_vector_type(8)));

// ---------------------------------------------------------------------------
// async global->LDS, 16B per lane (wave-uniform LDS base + lane*16)
// ---------------------------------------------------------------------------
__device__ __forceinline__ void gload16(const bf16_t* g, bf16_t* l)
{
    __builtin_amdgcn_global_load_lds(
        (const __attribute__((address_space(1))) void*)g,
        (__attribute__((address_space(3))) void*)l, 16, 0, 0);
}

// ---------------------------------------------------------------------------
// fp32 -> bf16 elementwise convert (8 elems/thread)
// ---------------------------------------------------------------------------
__global__ __launch_bounds__(256)
void cvt_bf16(const float* __restrict__ src, bf16_t* __restrict__ dst, int n)
{
    const int i = (blockIdx.x * 256 + threadIdx.x) * 8;
    if (i >= n) return;
    const float4 a = *reinterpret_cast<const float4*>(src + i);
    const float4 b = *reinterpret_cast<const float4*>(src + i + 4);
    bf16x8 o;
    o[0] = (bf16_t)a.x; o[1] = (bf16_t)a.y; o[2] = (bf16_t)a.z; o[3] = (bf16_t)a.w;
    o[4] = (bf16_t)b.x; o[5] = (bf16_t)b.y; o[6] = (bf16_t)b.z; o[7] = (bf16_t)b.w;
    *reinterpret_cast<bf16x8*>(dst + i) = o;
}

// ---------------------------------------------------------------------------
// fused all-input convert: concat(tctx,hs) then Wq|Wk|Wv, one contiguous dst.
// ---------------------------------------------------------------------------
__global__ __launch_bounds__(256)
void cvt_all(const float* __restrict__ tctx, const float* __restrict__ hs,
             const float* __restrict__ wq, const float* __restrict__ wk,
             const float* __restrict__ wv, bf16_t* __restrict__ dst)
{
    const int i = (blockIdx.x * 256 + threadIdx.x) * 8;
    const float* src;
    if (i < 8388608) {
        const int b = i >> 22;
        const int t = (i >> 11) & 2047;
        const int c = i & 2047;
        src = (t < 1024) ? (tctx + ((size_t)(b * 1024 + t) << 11) + c)
                         : (hs   + ((size_t)(b * 1024 + (t - 1024)) << 11) + c);
    } else {
        const int j = i - 8388608;
        if (j < 4194304)      src = wq + j;
        else if (j < 5242880) src = wk + (j - 4194304);
        else                  src = wv + (j - 5242880);
    }
    const float4 a = *reinterpret_cast<const float4*>(src);
    const float4 d = *reinterpret_cast<const float4*>(src + 4);
    bf16x8 o;
    o[0] = (bf16_t)a.x; o[1] = (bf16_t)a.y; o[2] = (bf16_t)a.z; o[3] = (bf16_t)a.w;
    o[4] = (bf16_t)d.x; o[5] = (bf16_t)d.y; o[6] = (bf16_t)d.z; o[7] = (bf16_t)d.w;
    *reinterpret_cast<bf16x8*>(dst + i) = o;
}

// ---------------------------------------------------------------------------
// Fused QKV projection GEMM v2: BM=BN=128, BK=32, 256 thr (4 waves 2x2),
// 3-buffer LDS pipeline, prefetch distance 2, counted vmcnt (never 0 in loop),
// ONE barrier per K-step. XCD-swizzled block ids (512 blocks, chunk 64).
// RMSNorm/RoPE epilogue for Q and K; Q scaled by 0.125*log2(e).
// ---------------------------------------------------------------------------
__global__ __launch_bounds__(256)
void gemm_qkv2(const bf16_t* __restrict__ Ain, const bf16_t* __restrict__ Wq_,
               bf16_t* __restrict__ Qo, bf16_t* __restrict__ KVo,
               const float* __restrict__ qg, const float* __restrict__ kg,
               const float* __restrict__ cosb, const float* __restrict__ sinb)
{
    __shared__ __align__(16) bf16_t Ads[3][4096];   // [128][32] x3
    __shared__ __align__(16) bf16_t Bds[3][4096];

    const int tid  = threadIdx.x;
    const int wave = tid >> 6;
    const int lane = tid & 63;

    const int bid = blockIdx.x;
    const int swz = (bid & 7) * 64 + (bid >> 3);
    const bool isQ = swz < 256;
    int m0, n0, NN;
    const bf16_t* Bw;
    bf16_t* C;
    if (isQ) { m0 = (swz & 15) << 7; n0 = (swz >> 4) << 7; NN = 2048; Bw = Wq_;           C = Qo; }
    else     { const int kb = swz - 256;
               m0 = (kb & 31) << 7;  n0 = (kb >> 5) << 7;  NN = 1024; Bw = Wq_ + 4194304; C = KVo; }

    const int wm = (wave >> 1) << 6;   // 0,64
    const int wn = (wave & 1) << 6;    // 0,64
    const int lr = lane & 15;
    const int lg = lane >> 4;

    const int sr = lane >> 2;          // 0..15
    const int sc = (lane & 3) << 3;    // 0,8,16,24
    size_t aoff[2], boff[2];
    #pragma unroll
    for (int cc = 0; cc < 2; ++cc) {
        const int am = m0 + wave * 32 + cc * 16 + sr;
        const int ar = isQ ? (((am >> 10) << 11) + 1024 + (am & 1023)) : am;
        aoff[cc] = (size_t)ar * HID + sc;
        boff[cc] = (size_t)(n0 + wave * 32 + cc * 16 + sr) * HID + sc;
    }

    f32x4 acc[4][4];
    #pragma unroll
    for (int i = 0; i < 4; ++i)
        #pragma unroll
        for (int j = 0; j < 4; ++j)
            #pragma unroll
            for (int r = 0; r < 4; ++r) acc[i][j][r] = 0.0f;

    auto STAGE = [&](int buf, int k0) {
        #pragma unroll
        for (int cc = 0; cc < 2; ++cc) {
            gload16(Ain + aoff[cc] + k0, &Ads[buf][(wave * 2 + cc) << 9]);
            gload16(Bw  + boff[cc] + k0, &Bds[buf][(wave * 2 + cc) << 9]);
        }
    };

    constexpr int nk = HID / 32;   // 64
    STAGE(0, 0);
    STAGE(1, 32);

    for (int t = 0; t < nk; ++t) {
        if (t < nk - 1) asm volatile("s_waitcnt vmcnt(4)" ::: "memory");
        else            asm volatile("s_waitcnt vmcnt(0)" ::: "memory");
        __builtin_amdgcn_s_barrier();
        __builtin_amdgcn_sched_barrier(0);

        const int buf = t % 3;
        bf16x8 af[4], bfr[4];
        #pragma unroll
        for (int i = 0; i < 4; ++i) {
            af[i]  = *reinterpret_cast<const bf16x8*>(&Ads[buf][(wm + i * 16 + lr) * 32 + lg * 8]);
            bfr[i] = *reinterpret_cast<const bf16x8*>(&Bds[buf][(wn + i * 16 + lr) * 32 + lg * 8]);
        }
        asm volatile("s_waitcnt lgkmcnt(0)" ::: "memory");
        __builtin_amdgcn_sched_barrier(0);

        if (t + 2 < nk) STAGE((t + 2) % 3, (t + 2) * 32);

        __builtin_amdgcn_s_setprio(1);
        #pragma unroll
        for (int mi = 0; mi < 4; ++mi)
            #pragma unroll
            for (int ni = 0; ni < 4; ++ni)
                acc[mi][ni] = __builtin_amdgcn_mfma_f32_16x16x32_bf16(
                    af[mi], bfr[ni], acc[mi][ni], 0, 0, 0);
        __builtin_amdgcn_s_setprio(0);
    }

    const int emode = isQ ? 1 : (((n0 + wn) < 512) ? 2 : 0);
    if (emode) {
        const float* gamma = (emode == 1) ? qg : kg;
        const float post = (emode == 1) ? (0.125f * 1.44269504088896f) : 1.0f;
        float g4[4];
        #pragma unroll
        for (int ni = 0; ni < 4; ++ni) g4[ni] = gamma[ni * 16 + lr];

        #pragma unroll
        for (int mi = 0; mi < 4; ++mi)
            #pragma unroll
            for (int r = 0; r < 4; ++r) {
                const int m = m0 + wm + mi * 16 + lg * 4 + r;
                float ss = 0.0f;
                #pragma unroll
                for (int ni = 0; ni < 4; ++ni) ss += acc[mi][ni][r] * acc[mi][ni][r];
                ss += __shfl_xor(ss, 1);
                ss += __shfl_xor(ss, 2);
                ss += __shfl_xor(ss, 4);
                ss += __shfl_xor(ss, 8);
                const float rn = rsqrtf(ss * (1.0f / 64.0f) + 1e-6f);
                int bb, pos;
                if (emode == 1) { bb = m >> 10; pos = 1024 + (m & 1023); }
                else            { bb = m >> 11; pos = m & 2047; }
                const float* cp = cosb + (((size_t)bb * 2048 + pos) << 6);
                const float* sp = sinb + (((size_t)bb * 2048 + pos) << 6);
                float qn[4];
                #pragma unroll
                for (int ni = 0; ni < 4; ++ni) qn[ni] = acc[mi][ni][r] * rn * g4[ni];
                #pragma unroll
                for (int ni = 0; ni < 4; ++ni) {
                    const float rot = (ni < 2) ? -qn[ni + 2] : qn[ni - 2];
                    acc[mi][ni][r] = (qn[ni] * cp[ni * 16 + lr] + rot * sp[ni * 16 + lr]) * post;
                }
            }
    }

    #pragma unroll
    for (int mi = 0; mi < 4; ++mi)
        #pragma unroll
        for (int r = 0; r < 4; ++r) {
            const int m = m0 + wm + mi * 16 + lg * 4 + r;
            bf16_t* crow = C + (size_t)m * NN + n0 + wn + lr;
            crow[0]  = (bf16_t)acc[mi][0][r];
            crow[16] = (bf16_t)acc[mi][1][r];
            crow[32] = (bf16_t)acc[mi][2][r];
            crow[48] = (bf16_t)acc[mi][3][r];
        }
}

// ---------------------------------------------------------------------------
// Out-projection GEMM v2: C[m,n] = sum_k A[m,k]*B[n,k], fp32 C.
// ---------------------------------------------------------------------------
__global__ __launch_bounds__(256)
void gemm_out2(const bf16_t* __restrict__ A, const bf16_t* __restrict__ Bw,
               float* __restrict__ C)
{
    __shared__ __align__(16) bf16_t Ads[3][2048];   // [64][32] x3
    __shared__ __align__(16) bf16_t Bds[3][4096];   // [128][32] x3

    const int tid  = threadIdx.x;
    const int wave = tid >> 6;
    const int lane = tid & 63;

    const int bid = blockIdx.x;
    const int swz = (bid & 7) * 64 + (bid >> 3);
    const int m0 = (swz & 31) << 6;
    const int n0 = (swz >> 5) << 7;

    const int wm = (wave >> 1) << 5;
    const int wn = (wave & 1) << 6;
    const int lr = lane & 15;
    const int lg = lane >> 4;

    const int sr = lane >> 2;
    const int sc = (lane & 3) << 3;

    const size_t aoff  = (size_t)(m0 + wave * 16 + sr) * HID + sc;
    size_t boff[2];
    #pragma unroll
    for (int cc = 0; cc < 2; ++cc)
        boff[cc] = (size_t)(n0 + wave * 32 + cc * 16 + sr) * HID + sc;

    f32x4 acc[2][4];
    #pragma unroll
    for (int i = 0; i < 2; ++i)
        #pragma unroll
        for (int j = 0; j < 4; ++j)
            #pragma unroll
            for (int r = 0; r < 4; ++r) acc[i][j][r] = 0.0f;

    auto STAGE = [&](int buf, int k0) {
        gload16(A + aoff + k0, &Ads[buf][wave << 9]);
        #pragma unroll
        for (int cc = 0; cc < 2; ++cc)
            gload16(Bw + boff[cc] + k0, &Bds[buf][(wave * 2 + cc) << 9]);
    };

    constexpr int nk = HID / 32;   // 64
    STAGE(0, 0);
    STAGE(1, 32);

    for (int t = 0; t < nk; ++t) {
        if (t < nk - 1) asm volatile("s_waitcnt vmcnt(3)" ::: "memory");
        else            asm volatile("s_waitcnt vmcnt(0)" ::: "memory");
        __builtin_amdgcn_s_barrier();
        __builtin_amdgcn_sched_barrier(0);

        const int buf = t % 3;
        bf16x8 af[2], bfr[4];
        #pragma unroll
        for (int i = 0; i < 2; ++i)
            af[i]  = *reinterpret_cast<const bf16x8*>(&Ads[buf][(wm + i * 16 + lr) * 32 + lg * 8]);
        #pragma unroll
        for (int i = 0; i < 4; ++i)
            bfr[i] = *reinterpret_cast<const bf16x8*>(&Bds[buf][(wn + i * 16 + lr) * 32 + lg * 8]);
        asm volatile("s_waitcnt lgkmcnt(0)" ::: "memory");
        __builtin_amdgcn_sched_barrier(0);

        if (t + 2 < nk) STAGE((t + 2) % 3, (t + 2) * 32);

        __builtin_amdgcn_s_setprio(1);
        #pragma unroll
        for (int mi = 0; mi < 2; ++mi)
            #pragma unroll
            for (int ni = 0; ni < 4; ++ni)
                acc[mi][ni] = __builtin_amdgcn_mfma_f32_16x16x32_bf16(
                    af[mi], bfr[ni], acc[mi][ni], 0, 0, 0);
        __builtin_amdgcn_s_setprio(0);
    }

    #pragma unroll
    for (int mi = 0; mi < 2; ++mi)
        #pragma unroll
        for (int r = 0; r < 4; ++r) {
            const int m = m0 + wm + mi * 16 + lg * 4 + r;
            float* crow = C + (size_t)m * 2048 + n0 + wn + lr;
            crow[0]  = acc[mi][0][r];
            crow[16] = acc[mi][1][r];
            crow[32] = acc[mi][2][r];
            crow[48] = acc[mi][3][r];
        }
}

// ---------------------------------------------------------------------------
// bf16 MFMA flash attention v8: KVBLK=128 + packed-V b128 reads.
// 8 waves (512 thr), QBLK=128 (wave owns 16 q-rows), KV tile 128,
// double-buffered K/V with register prefetch, ONE barrier per (128-key) tile
// (half the barriers of v7). Softmax: bare exp2 (Q pre-scaled; bias cancels).
// PV + l: mfma_f32_16x16x16bf16_1k with P as A-operand (zero exchange).
// V stored PACKED: Vp[d][p], p(t) = ((t>>2)&3)*32 + (t>>4)*4 + (t&3), so the
// B-frags of adjacent kt pairs are one contiguous 16B word -> V reads are
// ds_read_b128 (half the instruction count of b64 pairs); the two s16x4
// halves feed consecutive-kt MFMAs as register pairs (no extra VALU).
// LDS 69.6 KB -> 2 blocks/CU. Grid: (B*NH, Sq/128). Output in place over Q.
// ---------------------------------------------------------------------------
__global__ __launch_bounds__(512)
void flash_mfma(const bf16_t* __restrict__ Qb, const bf16_t* __restrict__ KVb,
                bf16_t* __restrict__ Ob)
{
    const int bh = blockIdx.x;
    const int b  = bh >> 5;
    const int h  = bh & 31;
    const int g  = h >> 2;
    const int q0 = blockIdx.y << 7;
    const int tid  = threadIdx.x;
    const int wave = tid >> 6;
    const int lane = tid & 63;
    const int lr = lane & 15;
    const int lg = lane >> 4;

    __shared__ __align__(16) bf16_t Kd[2][128][68];     // [k][d]
    __shared__ __align__(16) bf16_t Vp[2][64][136];     // [d][packed t]

    // staging assignment (512 threads): K 16 elems/thread, V 4 rows x 4 d
    const int kr = tid >> 2;            // K row 0..127
    const int kc = (tid & 3) << 4;      // K col 0,16,32,48
    const int tv = tid >> 4;            // V t-quad 0..31 (rows tv*4..+3)
    const int d0 = (tid & 15) << 2;     // V d-group
    const int p0 = (tv & 3) * 32 + (tv >> 2) * 4;   // packed col base

    const size_t kbase = (size_t)(b * Tt) * 1024 + g * 64;
    const bf16_t* kp = KVb + kbase + (size_t)kr * 1024 + kc;
    const bf16_t* vp = KVb + kbase + (size_t)(tv * 4) * 1024 + 512 + d0;

    // Q fragments (B-operand of S^T = K*Q^T); Q pre-scaled by Cs.
    bf16x8 qf[2];
    {
        const bf16_t* qp = Qb + (size_t)(b * Sq + q0 + wave * 16 + lr) * 2048 + h * 64 + lg * 8;
        qf[0] = *reinterpret_cast<const bf16x8*>(qp);
        qf[1] = *reinterpret_cast<const bf16x8*>(qp + 32);
    }

    s16x4 onesB;
    #pragma unroll
    for (int j = 0; j < 4; ++j) onesB[j] = (short)0x3F80;
    const f32x4 fz = {0.0f, 0.0f, 0.0f, 0.0f};

    f32x4 lacc = fz;
    f32x4 oacc[4];
    #pragma unroll
    for (int dt = 0; dt < 4; ++dt) oacc[dt] = fz;

    // prologue: load tile 0 into regs, write buf 0
    {
        const bf16x8 ka = *reinterpret_cast<const bf16x8*>(kp);
        const bf16x8 kb = *reinterpret_cast<const bf16x8*>(kp + 8);
        const bf16x4 v0 = *reinterpret_cast<const bf16x4*>(vp);
        const bf16x4 v1 = *reinterpret_cast<const bf16x4*>(vp + 1024);
        const bf16x4 v2 = *reinterpret_cast<const bf16x4*>(vp + 2048);
        const bf16x4 v3 = *reinterpret_cast<const bf16x4*>(vp + 3072);
        kp += 131072; vp += 131072;
        *reinterpret_cast<bf16x8*>(&Kd[0][kr][kc])     = ka;
        *reinterpret_cast<bf16x8*>(&Kd[0][kr][kc + 8]) = kb;
        #pragma unroll
        for (int j = 0; j < 4; ++j) {
            bf16x4 w; w[0] = v0[j]; w[1] = v1[j]; w[2] = v2[j]; w[3] = v3[j];
            *reinterpret_cast<bf16x4*>(&Vp[0][d0 + j][p0]) = w;
        }
    }
    __syncthreads();

#define FTILE(CUR, NXT, MORE)                                                  \
    {                                                                          \
        bf16x8 kan, kbn; bf16x4 v0n, v1n, v2n, v3n;                            \
        if (MORE) {                                                            \
            kan = *reinterpret_cast<const bf16x8*>(kp);                        \
            kbn = *reinterpret_cast<const bf16x8*>(kp + 8);                    \
            v0n = *reinterpret_cast<const bf16x4*>(vp);                        \
            v1n = *reinterpret_cast<const bf16x4*>(vp + 1024);                 \
            v2n = *reinterpret_cast<const bf16x4*>(vp + 2048);                 \
            v3n = *reinterpret_cast<const bf16x4*>(vp + 3072);                 \
            kp += 131072; vp += 131072;                                        \
        }                                                                      \
        f32x4 sc[8];                                                           \
        __builtin_amdgcn_s_setprio(1);                                         \
        _Pragma("unroll")                                                      \
        for (int kt = 0; kt < 8; ++kt) {                                       \
            const bf16x8 kf0 = *reinterpret_cast<const bf16x8*>(               \
                &Kd[CUR][kt * 16 + lr][lg * 8]);                               \
            const bf16x8 kf1 = *reinterpret_cast<const bf16x8*>(               \
                &Kd[CUR][kt * 16 + lr][32 + lg * 8]);                          \
            f32x4 z = __builtin_amdgcn_mfma_f32_16x16x32_bf16(                 \
                kf0, qf[0], fz, 0, 0, 0);                                      \
            z = __builtin_amdgcn_mfma_f32_16x16x32_bf16(kf1, qf[1], z, 0, 0, 0); \
            sc[kt] = z;                                                        \
        }                                                                      \
        __builtin_amdgcn_s_setprio(0);                                         \
        s16x4 pa[8];                                                           \
        _Pragma("unroll")                                                      \
        for (int kt = 0; kt < 8; ++kt) {                                       \
            bf16x4 pw;                                                         \
            _Pragma("unroll")                                                  \
            for (int j = 0; j < 4; ++j) pw[j] = (bf16_t)exp2f(sc[kt][j]);      \
            pa[kt] = *reinterpret_cast<s16x4*>(&pw);                           \
        }                                                                      \
        __builtin_amdgcn_s_setprio(1);                                         \
        _Pragma("unroll")                                                      \
        for (int dt = 0; dt < 4; ++dt)                                         \
            _Pragma("unroll")                                                  \
            for (int k8 = 0; k8 < 4; ++k8) {                                   \
                const s16x8 vv = *reinterpret_cast<const s16x8*>(              \
                    &Vp[CUR][dt * 16 + lr][lg * 32 + k8 * 8]);                 \
                const s16x4 vfA = {vv[0], vv[1], vv[2], vv[3]};                \
                const s16x4 vfB = {vv[4], vv[5], vv[6], vv[7]};                \
                oacc[dt] = __builtin_amdgcn_mfma_f32_16x16x16bf16_1k(          \
                    pa[2 * k8], vfA, oacc[dt], 0, 0, 0);                       \
                oacc[dt] = __builtin_amdgcn_mfma_f32_16x16x16bf16_1k(          \
                    pa[2 * k8 + 1], vfB, oacc[dt], 0, 0, 0);                   \
            }                                                                  \
        _Pragma("unroll")                                                      \
        for (int kt = 0; kt < 8; ++kt)                                         \
            lacc = __builtin_amdgcn_mfma_f32_16x16x16bf16_1k(                  \
                pa[kt], onesB, lacc, 0, 0, 0);                                 \
        __builtin_amdgcn_s_setprio(0);                                         \
        if (MORE) {                                                            \
            *reinterpret_cast<bf16x8*>(&Kd[NXT][kr][kc])     = kan;            \
            *reinterpret_cast<bf16x8*>(&Kd[NXT][kr][kc + 8]) = kbn;            \
            _Pragma("unroll")                                                  \
            for (int j = 0; j < 4; ++j) {                                      \
                bf16x4 w; w[0] = v0n[j]; w[1] = v1n[j]; w[2] = v2n[j]; w[3] = v3n[j]; \
                *reinterpret_cast<bf16x4*>(&Vp[NXT][d0 + j][p0]) = w;          \
            }                                                                  \
            __syncthreads();                                                   \
        }                                                                      \
    }

    // 16 KV tiles of 128 keys: 7 unrolled pairs + tiles 14, 15
    #pragma unroll 1
    for (int it = 0; it < 7; ++it) {
        FTILE(0, 1, 1)
        FTILE(1, 0, 1)
    }
    FTILE(0, 1, 1)
    FTILE(1, 0, 0)
#undef FTILE

    // finalize: lane holds O[q = lg*4+r][d = dt*16+lr], l[q] = lacc[r]
    f32x4 inv4;
    #pragma unroll
    for (int r = 0; r < 4; ++r) inv4[r] = 1.0f / lacc[r];
    #pragma unroll
    for (int r = 0; r < 4; ++r) {
        bf16_t* orow = Ob + (size_t)(b * Sq + q0 + wave * 16 + lg * 4 + r) * 2048 + h * 64 + lr;
        #pragma unroll
        for (int dt = 0; dt < 4; ++dt)
            orow[dt * 16] = (bf16_t)(oacc[dt][r] * inv4[r]);
    }
}

// ---------------------------------------------------------------------------
extern "C" void kernel_launch(void* const* d_in, const int* in_sizes, int n_in,
                              void* d_out, int out_size, void* d_ws, size_t ws_size,
                              hipStream_t stream)
{
    const float* hs   = (const float*)d_in[0];
    const float* tctx = (const float*)d_in[1];
    const float* cosb = (const float*)d_in[2];
    const float* sinb = (const float*)d_in[3];
    const float* Wq   = (const float*)d_in[4];
    const float* Wk   = (const float*)d_in[5];
    const float* Wv   = (const float*)d_in[6];
    const float* Wo   = (const float*)d_in[7];
    const float* qg   = (const float*)d_in[8];
    const float* kg   = (const float*)d_in[9];
    float* out = (float*)d_out;

    // workspace layout (bf16 elems): total 23,068,672 elems = 46.1 MB
    bf16_t* W     = (bf16_t*)d_ws;
    bf16_t* kvinb = W;                    // [B][2048][2048] concat: 8,388,608
    bf16_t* Wqb   = kvinb + 8388608;      // Wq (4,194,304) + Wkv (2,097,152)
    bf16_t* Qb    = Wqb + 6291456;        // q / attn in-place: 4,194,304
    bf16_t* KVb   = Qb + 4194304;         // k|v: 4,194,304
    bf16_t* Wob   = kvinb;                // reused after gemm_qkv2 consumes kvinb

    // fused converts: concat + all three projection weights (one launch)
    cvt_all<<<7168, 256, 0, stream>>>(tctx, hs, Wq, Wk, Wv, kvinb);

    // fused Q + KV projections with RMSNorm/RoPE(+Cs on Q) epilogue
    gemm_qkv2<<<512, 256, 0, stream>>>(kvinb, Wqb, Qb, KVb, qg, kg, cosb, sinb);

    // convert Wo into kvinb's space
    cvt_bf16<<<2048, 256, 0, stream>>>(Wo, Wob, 4194304);

    // flash attention (bf16 MFMA), bf16 output in place over Q
    flash_mfma<<<dim3(Bc * NH, Sq / 128), 512, 0, stream>>>(Qb, KVb, Qb);

    // output projection: attn(bf16) @ Wo^T -> fp32 out
    gemm_out2<<<512, 256, 0, stream>>>(Qb, Wob, out);
}

// Round 15
// 156.794 us; speedup vs baseline: 1.0939x; 1.0939x over previous
//
#include <hip/hip_runtime.h>
#include <hip/hip_bf16.h>

// Problem constants
constexpr int Bc  = 2;
constexpr int Sq  = 1024;   // query seq len
constexpr int CTX = 1024;
constexpr int Tt  = 2048;   // total kv len
constexpr int HID = 2048;
constexpr int NH  = 32;
constexpr int NKV = 8;
constexpr int HD  = 64;

typedef __bf16 bf16_t;
typedef bf16_t bf16x8 __attribute__((ext_vector_type(8)));
typedef bf16_t bf16x4 __attribute__((ext_vector_type(4)));
typedef bf16_t bf16x2 __attribute__((ext_vector_type(2)));
typedef float  f32x4  __attribute__((ext_vector_type(4)));
typedef short  s16x4  __attribute__((ext_vector_type(4)));

// ---------------------------------------------------------------------------
// async global->LDS, 16B per lane (wave-uniform LDS base + lane*16)
// ---------------------------------------------------------------------------
__device__ __forceinline__ void gload16(const bf16_t* g, bf16_t* l)
{
    __builtin_amdgcn_global_load_lds(
        (const __attribute__((address_space(1))) void*)g,
        (__attribute__((address_space(3))) void*)l, 16, 0, 0);
}

// ---------------------------------------------------------------------------
// fp32 -> bf16 elementwise convert (8 elems/thread)
// ---------------------------------------------------------------------------
__global__ __launch_bounds__(256)
void cvt_bf16(const float* __restrict__ src, bf16_t* __restrict__ dst, int n)
{
    const int i = (blockIdx.x * 256 + threadIdx.x) * 8;
    if (i >= n) return;
    const float4 a = *reinterpret_cast<const float4*>(src + i);
    const float4 b = *reinterpret_cast<const float4*>(src + i + 4);
    bf16x8 o;
    o[0] = (bf16_t)a.x; o[1] = (bf16_t)a.y; o[2] = (bf16_t)a.z; o[3] = (bf16_t)a.w;
    o[4] = (bf16_t)b.x; o[5] = (bf16_t)b.y; o[6] = (bf16_t)b.z; o[7] = (bf16_t)b.w;
    *reinterpret_cast<bf16x8*>(dst + i) = o;
}

// ---------------------------------------------------------------------------
// fused all-input convert: concat(tctx,hs) then Wq|Wk|Wv, one contiguous dst.
// ---------------------------------------------------------------------------
__global__ __launch_bounds__(256)
void cvt_all(const float* __restrict__ tctx, const float* __restrict__ hs,
             const float* __restrict__ wq, const float* __restrict__ wk,
             const float* __restrict__ wv, bf16_t* __restrict__ dst)
{
    const int i = (blockIdx.x * 256 + threadIdx.x) * 8;
    const float* src;
    if (i < 8388608) {
        const int b = i >> 22;
        const int t = (i >> 11) & 2047;
        const int c = i & 2047;
        src = (t < 1024) ? (tctx + ((size_t)(b * 1024 + t) << 11) + c)
                         : (hs   + ((size_t)(b * 1024 + (t - 1024)) << 11) + c);
    } else {
        const int j = i - 8388608;
        if (j < 4194304)      src = wq + j;
        else if (j < 5242880) src = wk + (j - 4194304);
        else                  src = wv + (j - 5242880);
    }
    const float4 a = *reinterpret_cast<const float4*>(src);
    const float4 d = *reinterpret_cast<const float4*>(src + 4);
    bf16x8 o;
    o[0] = (bf16_t)a.x; o[1] = (bf16_t)a.y; o[2] = (bf16_t)a.z; o[3] = (bf16_t)a.w;
    o[4] = (bf16_t)d.x; o[5] = (bf16_t)d.y; o[6] = (bf16_t)d.z; o[7] = (bf16_t)d.w;
    *reinterpret_cast<bf16x8*>(dst + i) = o;
}

// ---------------------------------------------------------------------------
// Fused QKV projection GEMM v2: BM=BN=128, BK=32, 256 thr (4 waves 2x2),
// 3-buffer LDS pipeline, prefetch distance 2, counted vmcnt (never 0 in loop),
// ONE barrier per K-step. XCD-swizzled block ids (512 blocks, chunk 64).
// RMSNorm/RoPE epilogue for Q and K; Q scaled by 0.125*log2(e).
// ---------------------------------------------------------------------------
__global__ __launch_bounds__(256)
void gemm_qkv2(const bf16_t* __restrict__ Ain, const bf16_t* __restrict__ Wq_,
               bf16_t* __restrict__ Qo, bf16_t* __restrict__ KVo,
               const float* __restrict__ qg, const float* __restrict__ kg,
               const float* __restrict__ cosb, const float* __restrict__ sinb)
{
    __shared__ __align__(16) bf16_t Ads[3][4096];   // [128][32] x3
    __shared__ __align__(16) bf16_t Bds[3][4096];

    const int tid  = threadIdx.x;
    const int wave = tid >> 6;
    const int lane = tid & 63;

    const int bid = blockIdx.x;
    const int swz = (bid & 7) * 64 + (bid >> 3);
    const bool isQ = swz < 256;
    int m0, n0, NN;
    const bf16_t* Bw;
    bf16_t* C;
    if (isQ) { m0 = (swz & 15) << 7; n0 = (swz >> 4) << 7; NN = 2048; Bw = Wq_;           C = Qo; }
    else     { const int kb = swz - 256;
               m0 = (kb & 31) << 7;  n0 = (kb >> 5) << 7;  NN = 1024; Bw = Wq_ + 4194304; C = KVo; }

    const int wm = (wave >> 1) << 6;   // 0,64
    const int wn = (wave & 1) << 6;    // 0,64
    const int lr = lane & 15;
    const int lg = lane >> 4;

    const int sr = lane >> 2;          // 0..15
    const int sc = (lane & 3) << 3;    // 0,8,16,24
    size_t aoff[2], boff[2];
    #pragma unroll
    for (int cc = 0; cc < 2; ++cc) {
        const int am = m0 + wave * 32 + cc * 16 + sr;
        const int ar = isQ ? (((am >> 10) << 11) + 1024 + (am & 1023)) : am;
        aoff[cc] = (size_t)ar * HID + sc;
        boff[cc] = (size_t)(n0 + wave * 32 + cc * 16 + sr) * HID + sc;
    }

    f32x4 acc[4][4];
    #pragma unroll
    for (int i = 0; i < 4; ++i)
        #pragma unroll
        for (int j = 0; j < 4; ++j)
            #pragma unroll
            for (int r = 0; r < 4; ++r) acc[i][j][r] = 0.0f;

    auto STAGE = [&](int buf, int k0) {
        #pragma unroll
        for (int cc = 0; cc < 2; ++cc) {
            gload16(Ain + aoff[cc] + k0, &Ads[buf][(wave * 2 + cc) << 9]);
            gload16(Bw  + boff[cc] + k0, &Bds[buf][(wave * 2 + cc) << 9]);
        }
    };

    constexpr int nk = HID / 32;   // 64
    STAGE(0, 0);
    STAGE(1, 32);

    for (int t = 0; t < nk; ++t) {
        if (t < nk - 1) asm volatile("s_waitcnt vmcnt(4)" ::: "memory");
        else            asm volatile("s_waitcnt vmcnt(0)" ::: "memory");
        __builtin_amdgcn_s_barrier();
        __builtin_amdgcn_sched_barrier(0);

        const int buf = t % 3;
        bf16x8 af[4], bfr[4];
        #pragma unroll
        for (int i = 0; i < 4; ++i) {
            af[i]  = *reinterpret_cast<const bf16x8*>(&Ads[buf][(wm + i * 16 + lr) * 32 + lg * 8]);
            bfr[i] = *reinterpret_cast<const bf16x8*>(&Bds[buf][(wn + i * 16 + lr) * 32 + lg * 8]);
        }
        asm volatile("s_waitcnt lgkmcnt(0)" ::: "memory");
        __builtin_amdgcn_sched_barrier(0);

        if (t + 2 < nk) STAGE((t + 2) % 3, (t + 2) * 32);

        __builtin_amdgcn_s_setprio(1);
        #pragma unroll
        for (int mi = 0; mi < 4; ++mi)
            #pragma unroll
            for (int ni = 0; ni < 4; ++ni)
                acc[mi][ni] = __builtin_amdgcn_mfma_f32_16x16x32_bf16(
                    af[mi], bfr[ni], acc[mi][ni], 0, 0, 0);
        __builtin_amdgcn_s_setprio(0);
    }

    const int emode = isQ ? 1 : (((n0 + wn) < 512) ? 2 : 0);
    if (emode) {
        const float* gamma = (emode == 1) ? qg : kg;
        const float post = (emode == 1) ? (0.125f * 1.44269504088896f) : 1.0f;
        float g4[4];
        #pragma unroll
        for (int ni = 0; ni < 4; ++ni) g4[ni] = gamma[ni * 16 + lr];

        #pragma unroll
        for (int mi = 0; mi < 4; ++mi)
            #pragma unroll
            for (int r = 0; r < 4; ++r) {
                const int m = m0 + wm + mi * 16 + lg * 4 + r;
                float ss = 0.0f;
                #pragma unroll
                for (int ni = 0; ni < 4; ++ni) ss += acc[mi][ni][r] * acc[mi][ni][r];
                ss += __shfl_xor(ss, 1);
                ss += __shfl_xor(ss, 2);
                ss += __shfl_xor(ss, 4);
                ss += __shfl_xor(ss, 8);
                const float rn = rsqrtf(ss * (1.0f / 64.0f) + 1e-6f);
                int bb, pos;
                if (emode == 1) { bb = m >> 10; pos = 1024 + (m & 1023); }
                else            { bb = m >> 11; pos = m & 2047; }
                const float* cp = cosb + (((size_t)bb * 2048 + pos) << 6);
                const float* sp = sinb + (((size_t)bb * 2048 + pos) << 6);
                float qn[4];
                #pragma unroll
                for (int ni = 0; ni < 4; ++ni) qn[ni] = acc[mi][ni][r] * rn * g4[ni];
                #pragma unroll
                for (int ni = 0; ni < 4; ++ni) {
                    const float rot = (ni < 2) ? -qn[ni + 2] : qn[ni - 2];
                    acc[mi][ni][r] = (qn[ni] * cp[ni * 16 + lr] + rot * sp[ni * 16 + lr]) * post;
                }
            }
    }

    #pragma unroll
    for (int mi = 0; mi < 4; ++mi)
        #pragma unroll
        for (int r = 0; r < 4; ++r) {
            const int m = m0 + wm + mi * 16 + lg * 4 + r;
            bf16_t* crow = C + (size_t)m * NN + n0 + wn + lr;
            crow[0]  = (bf16_t)acc[mi][0][r];
            crow[16] = (bf16_t)acc[mi][1][r];
            crow[32] = (bf16_t)acc[mi][2][r];
            crow[48] = (bf16_t)acc[mi][3][r];
        }
}

// ---------------------------------------------------------------------------
// Out-projection GEMM v2: C[m,n] = sum_k A[m,k]*B[n,k], fp32 C.
// ---------------------------------------------------------------------------
__global__ __launch_bounds__(256)
void gemm_out2(const bf16_t* __restrict__ A, const bf16_t* __restrict__ Bw,
               float* __restrict__ C)
{
    __shared__ __align__(16) bf16_t Ads[3][2048];   // [64][32] x3
    __shared__ __align__(16) bf16_t Bds[3][4096];   // [128][32] x3

    const int tid  = threadIdx.x;
    const int wave = tid >> 6;
    const int lane = tid & 63;

    const int bid = blockIdx.x;
    const int swz = (bid & 7) * 64 + (bid >> 3);
    const int m0 = (swz & 31) << 6;
    const int n0 = (swz >> 5) << 7;

    const int wm = (wave >> 1) << 5;
    const int wn = (wave & 1) << 6;
    const int lr = lane & 15;
    const int lg = lane >> 4;

    const int sr = lane >> 2;
    const int sc = (lane & 3) << 3;

    const size_t aoff  = (size_t)(m0 + wave * 16 + sr) * HID + sc;
    size_t boff[2];
    #pragma unroll
    for (int cc = 0; cc < 2; ++cc)
        boff[cc] = (size_t)(n0 + wave * 32 + cc * 16 + sr) * HID + sc;

    f32x4 acc[2][4];
    #pragma unroll
    for (int i = 0; i < 2; ++i)
        #pragma unroll
        for (int j = 0; j < 4; ++j)
            #pragma unroll
            for (int r = 0; r < 4; ++r) acc[i][j][r] = 0.0f;

    auto STAGE = [&](int buf, int k0) {
        gload16(A + aoff + k0, &Ads[buf][wave << 9]);
        #pragma unroll
        for (int cc = 0; cc < 2; ++cc)
            gload16(Bw + boff[cc] + k0, &Bds[buf][(wave * 2 + cc) << 9]);
    };

    constexpr int nk = HID / 32;   // 64
    STAGE(0, 0);
    STAGE(1, 32);

    for (int t = 0; t < nk; ++t) {
        if (t < nk - 1) asm volatile("s_waitcnt vmcnt(3)" ::: "memory");
        else            asm volatile("s_waitcnt vmcnt(0)" ::: "memory");
        __builtin_amdgcn_s_barrier();
        __builtin_amdgcn_sched_barrier(0);

        const int buf = t % 3;
        bf16x8 af[2], bfr[4];
        #pragma unroll
        for (int i = 0; i < 2; ++i)
            af[i]  = *reinterpret_cast<const bf16x8*>(&Ads[buf][(wm + i * 16 + lr) * 32 + lg * 8]);
        #pragma unroll
        for (int i = 0; i < 4; ++i)
            bfr[i] = *reinterpret_cast<const bf16x8*>(&Bds[buf][(wn + i * 16 + lr) * 32 + lg * 8]);
        asm volatile("s_waitcnt lgkmcnt(0)" ::: "memory");
        __builtin_amdgcn_sched_barrier(0);

        if (t + 2 < nk) STAGE((t + 2) % 3, (t + 2) * 32);

        __builtin_amdgcn_s_setprio(1);
        #pragma unroll
        for (int mi = 0; mi < 2; ++mi)
            #pragma unroll
            for (int ni = 0; ni < 4; ++ni)
                acc[mi][ni] = __builtin_amdgcn_mfma_f32_16x16x32_bf16(
                    af[mi], bfr[ni], acc[mi][ni], 0, 0, 0);
        __builtin_amdgcn_s_setprio(0);
    }

    #pragma unroll
    for (int mi = 0; mi < 2; ++mi)
        #pragma unroll
        for (int r = 0; r < 4; ++r) {
            const int m = m0 + wm + mi * 16 + lg * 4 + r;
            float* crow = C + (size_t)m * 2048 + n0 + wn + lr;
            crow[0]  = acc[mi][0][r];
            crow[16] = acc[mi][1][r];
            crow[32] = acc[mi][2][r];
            crow[48] = acc[mi][3][r];
        }
}

// ---------------------------------------------------------------------------
// bf16 MFMA flash attention (r12 version -- best measured: 71.0us).
// 8 waves (512 thr), QBLK=128 (wave owns 16 q-rows), KV tile 64,
// double-buffered K/V with register prefetch, ONE barrier per tile.
// Softmax: bare exp2 (Q pre-scaled by 0.125*log2e; 2^bias cancels in ratio).
// PV + l: mfma_f32_16x16x16bf16_1k with P as the A-operand (QK^T C-layout ==
// 16x16x16 A-frag layout, zero exchange). V consumed as b64 B-frags from the
// [d][t] layout. No s_setprio: this is a barrier-synced lockstep structure
// (m190: setprio hurts lockstep; helps only independent-wave kernels).
// History: static-unroll (r13, 74us), KVBLK=128 (r14, 93us), 4-wave/32q
// (r11, 86us), split-T (r9, 82us) all regressed vs this shape.
// Grid: (B*NH, Sq/128). Output bf16 in place over Q.
// ---------------------------------------------------------------------------
__global__ __launch_bounds__(512)
void flash_mfma(const bf16_t* __restrict__ Qb, const bf16_t* __restrict__ KVb,
                bf16_t* __restrict__ Ob)
{
    const int bh = blockIdx.x;
    const int b  = bh >> 5;
    const int h  = bh & 31;
    const int g  = h >> 2;
    const int q0 = blockIdx.y << 7;
    const int tid  = threadIdx.x;
    const int wave = tid >> 6;
    const int lane = tid & 63;
    const int lr = lane & 15;
    const int lg = lane >> 4;

    __shared__ __align__(16) bf16_t Kd[2][64][68];      // [k][d]
    __shared__ __align__(16) bf16_t Vd[2][64][68];      // [d][t]

    // staging assignment (block-wide, 512 threads)
    const int kr = tid >> 3;            // K row 0..63
    const int kc = (tid & 7) << 3;      // K col 0,8,..,56
    const int tp = tid >> 4;            // V t-pair 0..31
    const int d0 = (tid & 15) << 2;     // V d-group

    const size_t kbase = (size_t)(b * Tt) * 1024 + g * 64;

    // Q fragments (B-operand of S^T = K*Q^T); Q pre-scaled by Cs.
    bf16x8 qf[2];
    {
        const bf16_t* qp = Qb + (size_t)(b * Sq + q0 + wave * 16 + lr) * 2048 + h * 64 + lg * 8;
        qf[0] = *reinterpret_cast<const bf16x8*>(qp);
        qf[1] = *reinterpret_cast<const bf16x8*>(qp + 32);
    }

    // ones B-fragment (bf16 1.0) for the l row-sum MFMA
    s16x4 onesB;
    #pragma unroll
    for (int j = 0; j < 4; ++j) onesB[j] = (short)0x3F80;

    f32x4 lacc;
    #pragma unroll
    for (int j = 0; j < 4; ++j) lacc[j] = 0.0f;
    f32x4 oacc[4];
    #pragma unroll
    for (int dt = 0; dt < 4; ++dt)
        #pragma unroll
        for (int j = 0; j < 4; ++j) oacc[dt][j] = 0.0f;

    // prologue: load tile 0 into regs, write buf 0
    bf16x8 kreg;
    bf16x4 vr0, vr1;
    {
        kreg = *reinterpret_cast<const bf16x8*>(KVb + kbase + (size_t)kr * 1024 + kc);
        const bf16_t* vp = KVb + kbase + (size_t)(tp * 2) * 1024 + 512 + d0;
        vr0 = *reinterpret_cast<const bf16x4*>(vp);
        vr1 = *reinterpret_cast<const bf16x4*>(vp + 1024);
    }
    *reinterpret_cast<bf16x8*>(&Kd[0][kr][kc]) = kreg;
    #pragma unroll
    for (int j = 0; j < 4; ++j) {
        bf16x2 w; w[0] = vr0[j]; w[1] = vr1[j];
        *reinterpret_cast<bf16x2*>(&Vd[0][d0 + j][tp * 2]) = w;
    }
    __syncthreads();

    int cur = 0;

    for (int t0 = 0; t0 < Tt; t0 += 64) {
        const bool more = (t0 + 64 < Tt);
        if (more) {
            const size_t tb = kbase + (size_t)(t0 + 64) * 1024;
            kreg = *reinterpret_cast<const bf16x8*>(KVb + tb + (size_t)kr * 1024 + kc);
            const bf16_t* vp = KVb + tb + (size_t)(tp * 2) * 1024 + 512 + d0;
            vr0 = *reinterpret_cast<const bf16x4*>(vp);
            vr1 = *reinterpret_cast<const bf16x4*>(vp + 1024);
        }

        // QK^T (swapped): S^T = K * Q^T (already in log2 units)
        f32x4 sc[4];
        #pragma unroll
        for (int kt = 0; kt < 4; ++kt) {
            f32x4 z;
            #pragma unroll
            for (int j = 0; j < 4; ++j) z[j] = 0.0f;
            const bf16x8 kf0 = *reinterpret_cast<const bf16x8*>(&Kd[cur][kt * 16 + lr][lg * 8]);
            const bf16x8 kf1 = *reinterpret_cast<const bf16x8*>(&Kd[cur][kt * 16 + lr][32 + lg * 8]);
            z = __builtin_amdgcn_mfma_f32_16x16x32_bf16(kf0, qf[0], z, 0, 0, 0);
            z = __builtin_amdgcn_mfma_f32_16x16x32_bf16(kf1, qf[1], z, 0, 0, 0);
            sc[kt] = z;
        }

        // bare-exp2 softmax -> bf16 P packed directly as 16x16x16 A-frags
        s16x4 pa[4];
        #pragma unroll
        for (int kt = 0; kt < 4; ++kt) {
            bf16x4 pw;
            #pragma unroll
            for (int j = 0; j < 4; ++j) pw[j] = (bf16_t)exp2f(sc[kt][j]);
            pa[kt] = *reinterpret_cast<s16x4*>(&pw);
        }

        // PV: O = P * V via 16x16x16 (P is the A-operand, zero exchange);
        // V B-frags read b64 from the [d][t] layout.
        #pragma unroll
        for (int dt = 0; dt < 4; ++dt)
            #pragma unroll
            for (int kt = 0; kt < 4; ++kt) {
                const s16x4 vf = *reinterpret_cast<const s16x4*>(
                    &Vd[cur][dt * 16 + lr][kt * 16 + lg * 4]);
                oacc[dt] = __builtin_amdgcn_mfma_f32_16x16x16bf16_1k(
                    pa[kt], vf, oacc[dt], 0, 0, 0);
            }
        // l row-sum on the matrix pipe (B = ones)
        #pragma unroll
        for (int kt = 0; kt < 4; ++kt)
            lacc = __builtin_amdgcn_mfma_f32_16x16x16bf16_1k(pa[kt], onesB, lacc, 0, 0, 0);

        // stage next tile into the other buffer; single barrier per tile
        if (more) {
            *reinterpret_cast<bf16x8*>(&Kd[cur ^ 1][kr][kc]) = kreg;
            #pragma unroll
            for (int j = 0; j < 4; ++j) {
                bf16x2 w; w[0] = vr0[j]; w[1] = vr1[j];
                *reinterpret_cast<bf16x2*>(&Vd[cur ^ 1][d0 + j][tp * 2]) = w;
            }
            __syncthreads();
        }
        cur ^= 1;
    }

    // finalize: lane holds O[q = lg*4+r][d = dt*16+lr], l[q] = lacc[r];
    // write bf16 in place over Q.
    f32x4 inv4;
    #pragma unroll
    for (int r = 0; r < 4; ++r) inv4[r] = 1.0f / lacc[r];
    #pragma unroll
    for (int r = 0; r < 4; ++r) {
        bf16_t* orow = Ob + (size_t)(b * Sq + q0 + wave * 16 + lg * 4 + r) * 2048 + h * 64 + lr;
        #pragma unroll
        for (int dt = 0; dt < 4; ++dt)
            orow[dt * 16] = (bf16_t)(oacc[dt][r] * inv4[r]);
    }
}

// ---------------------------------------------------------------------------
extern "C" void kernel_launch(void* const* d_in, const int* in_sizes, int n_in,
                              void* d_out, int out_size, void* d_ws, size_t ws_size,
                              hipStream_t stream)
{
    const float* hs   = (const float*)d_in[0];
    const float* tctx = (const float*)d_in[1];
    const float* cosb = (const float*)d_in[2];
    const float* sinb = (const float*)d_in[3];
    const float* Wq   = (const float*)d_in[4];
    const float* Wk   = (const float*)d_in[5];
    const float* Wv   = (const float*)d_in[6];
    const float* Wo   = (const float*)d_in[7];
    const float* qg   = (const float*)d_in[8];
    const float* kg   = (const float*)d_in[9];
    float* out = (float*)d_out;

    // workspace layout (bf16 elems): total 23,068,672 elems = 46.1 MB
    bf16_t* W     = (bf16_t*)d_ws;
    bf16_t* kvinb = W;                    // [B][2048][2048] concat: 8,388,608
    bf16_t* Wqb   = kvinb + 8388608;      // Wq (4,194,304) + Wkv (2,097,152)
    bf16_t* Qb    = Wqb + 6291456;        // q / attn in-place: 4,194,304
    bf16_t* KVb   = Qb + 4194304;         // k|v: 4,194,304
    bf16_t* Wob   = kvinb;                // reused after gemm_qkv2 consumes kvinb

    // fused converts: concat + all three projection weights (one launch)
    cvt_all<<<7168, 256, 0, stream>>>(tctx, hs, Wq, Wk, Wv, kvinb);

    // fused Q + KV projections with RMSNorm/RoPE(+Cs on Q) epilogue
    gemm_qkv2<<<512, 256, 0, stream>>>(kvinb, Wqb, Qb, KVb, qg, kg, cosb, sinb);

    // convert Wo into kvinb's space
    cvt_bf16<<<2048, 256, 0, stream>>>(Wo, Wob, 4194304);

    // flash attention (bf16 MFMA), bf16 output in place over Q
    flash_mfma<<<dim3(Bc * NH, Sq / 128), 512, 0, stream>>>(Qb, KVb, Qb);

    // output projection: attn(bf16) @ Wo^T -> fp32 out
    gemm_out2<<<512, 256, 0, stream>>>(Qb, Wob, out);
}

// Round 16
// 151.937 us; speedup vs baseline: 1.1288x; 1.0320x over previous
//
#include <hip/hip_runtime.h>
#include <hip/hip_bf16.h>

// Problem constants
constexpr int Bc  = 2;
constexpr int Sq  = 1024;   // query seq len
constexpr int CTX = 1024;
constexpr int Tt  = 2048;   // total kv len
constexpr int HID = 2048;
constexpr int NH  = 32;
constexpr int NKV = 8;
constexpr int HD  = 64;

typedef __bf16 bf16_t;
typedef bf16_t bf16x8 __attribute__((ext_vector_type(8)));
typedef bf16_t bf16x4 __attribute__((ext_vector_type(4)));
typedef bf16_t bf16x2 __attribute__((ext_vector_type(2)));
typedef float  f32x4  __attribute__((ext_vector_type(4)));
typedef short  s16x4  __attribute__((ext_vector_type(4)));

// ---------------------------------------------------------------------------
// async global->LDS, 16B per lane (wave-uniform LDS base + lane*16)
// ---------------------------------------------------------------------------
__device__ __forceinline__ void gload16(const bf16_t* g, bf16_t* l)
{
    __builtin_amdgcn_global_load_lds(
        (const __attribute__((address_space(1))) void*)g,
        (__attribute__((address_space(3))) void*)l, 16, 0, 0);
}

// ---------------------------------------------------------------------------
// fp32 -> bf16 elementwise convert (8 elems/thread)
// ---------------------------------------------------------------------------
__global__ __launch_bounds__(256)
void cvt_bf16(const float* __restrict__ src, bf16_t* __restrict__ dst, int n)
{
    const int i = (blockIdx.x * 256 + threadIdx.x) * 8;
    if (i >= n) return;
    const float4 a = *reinterpret_cast<const float4*>(src + i);
    const float4 b = *reinterpret_cast<const float4*>(src + i + 4);
    bf16x8 o;
    o[0] = (bf16_t)a.x; o[1] = (bf16_t)a.y; o[2] = (bf16_t)a.z; o[3] = (bf16_t)a.w;
    o[4] = (bf16_t)b.x; o[5] = (bf16_t)b.y; o[6] = (bf16_t)b.z; o[7] = (bf16_t)b.w;
    *reinterpret_cast<bf16x8*>(dst + i) = o;
}

// ---------------------------------------------------------------------------
// fused all-input convert: concat(tctx,hs) then Wq|Wk|Wv, one contiguous dst.
// ---------------------------------------------------------------------------
__global__ __launch_bounds__(256)
void cvt_all(const float* __restrict__ tctx, const float* __restrict__ hs,
             const float* __restrict__ wq, const float* __restrict__ wk,
             const float* __restrict__ wv, bf16_t* __restrict__ dst)
{
    const int i = (blockIdx.x * 256 + threadIdx.x) * 8;
    const float* src;
    if (i < 8388608) {
        const int b = i >> 22;
        const int t = (i >> 11) & 2047;
        const int c = i & 2047;
        src = (t < 1024) ? (tctx + ((size_t)(b * 1024 + t) << 11) + c)
                         : (hs   + ((size_t)(b * 1024 + (t - 1024)) << 11) + c);
    } else {
        const int j = i - 8388608;
        if (j < 4194304)      src = wq + j;
        else if (j < 5242880) src = wk + (j - 4194304);
        else                  src = wv + (j - 5242880);
    }
    const float4 a = *reinterpret_cast<const float4*>(src);
    const float4 d = *reinterpret_cast<const float4*>(src + 4);
    bf16x8 o;
    o[0] = (bf16_t)a.x; o[1] = (bf16_t)a.y; o[2] = (bf16_t)a.z; o[3] = (bf16_t)a.w;
    o[4] = (bf16_t)d.x; o[5] = (bf16_t)d.y; o[6] = (bf16_t)d.z; o[7] = (bf16_t)d.w;
    *reinterpret_cast<bf16x8*>(dst + i) = o;
}

// ---------------------------------------------------------------------------
// Fused QKV projection GEMM v2: BM=BN=128, BK=32, 256 thr (4 waves 2x2),
// 3-buffer LDS pipeline, prefetch distance 2, counted vmcnt (never 0 in loop),
// ONE barrier per K-step. XCD-swizzled block ids (512 blocks, chunk 64).
// RMSNorm/RoPE epilogue for Q and K; Q scaled by 0.125*log2(e).
// ---------------------------------------------------------------------------
__global__ __launch_bounds__(256)
void gemm_qkv2(const bf16_t* __restrict__ Ain, const bf16_t* __restrict__ Wq_,
               bf16_t* __restrict__ Qo, bf16_t* __restrict__ KVo,
               const float* __restrict__ qg, const float* __restrict__ kg,
               const float* __restrict__ cosb, const float* __restrict__ sinb)
{
    __shared__ __align__(16) bf16_t Ads[3][4096];   // [128][32] x3
    __shared__ __align__(16) bf16_t Bds[3][4096];

    const int tid  = threadIdx.x;
    const int wave = tid >> 6;
    const int lane = tid & 63;

    const int bid = blockIdx.x;
    const int swz = (bid & 7) * 64 + (bid >> 3);
    const bool isQ = swz < 256;
    int m0, n0, NN;
    const bf16_t* Bw;
    bf16_t* C;
    if (isQ) { m0 = (swz & 15) << 7; n0 = (swz >> 4) << 7; NN = 2048; Bw = Wq_;           C = Qo; }
    else     { const int kb = swz - 256;
               m0 = (kb & 31) << 7;  n0 = (kb >> 5) << 7;  NN = 1024; Bw = Wq_ + 4194304; C = KVo; }

    const int wm = (wave >> 1) << 6;   // 0,64
    const int wn = (wave & 1) << 6;    // 0,64
    const int lr = lane & 15;
    const int lg = lane >> 4;

    const int sr = lane >> 2;          // 0..15
    const int sc = (lane & 3) << 3;    // 0,8,16,24
    size_t aoff[2], boff[2];
    #pragma unroll
    for (int cc = 0; cc < 2; ++cc) {
        const int am = m0 + wave * 32 + cc * 16 + sr;
        const int ar = isQ ? (((am >> 10) << 11) + 1024 + (am & 1023)) : am;
        aoff[cc] = (size_t)ar * HID + sc;
        boff[cc] = (size_t)(n0 + wave * 32 + cc * 16 + sr) * HID + sc;
    }

    f32x4 acc[4][4];
    #pragma unroll
    for (int i = 0; i < 4; ++i)
        #pragma unroll
        for (int j = 0; j < 4; ++j)
            #pragma unroll
            for (int r = 0; r < 4; ++r) acc[i][j][r] = 0.0f;

    auto STAGE = [&](int buf, int k0) {
        #pragma unroll
        for (int cc = 0; cc < 2; ++cc) {
            gload16(Ain + aoff[cc] + k0, &Ads[buf][(wave * 2 + cc) << 9]);
            gload16(Bw  + boff[cc] + k0, &Bds[buf][(wave * 2 + cc) << 9]);
        }
    };

    constexpr int nk = HID / 32;   // 64
    STAGE(0, 0);
    STAGE(1, 32);

    for (int t = 0; t < nk; ++t) {
        if (t < nk - 1) asm volatile("s_waitcnt vmcnt(4)" ::: "memory");
        else            asm volatile("s_waitcnt vmcnt(0)" ::: "memory");
        __builtin_amdgcn_s_barrier();
        __builtin_amdgcn_sched_barrier(0);

        const int buf = t % 3;
        bf16x8 af[4], bfr[4];
        #pragma unroll
        for (int i = 0; i < 4; ++i) {
            af[i]  = *reinterpret_cast<const bf16x8*>(&Ads[buf][(wm + i * 16 + lr) * 32 + lg * 8]);
            bfr[i] = *reinterpret_cast<const bf16x8*>(&Bds[buf][(wn + i * 16 + lr) * 32 + lg * 8]);
        }
        asm volatile("s_waitcnt lgkmcnt(0)" ::: "memory");
        __builtin_amdgcn_sched_barrier(0);

        if (t + 2 < nk) STAGE((t + 2) % 3, (t + 2) * 32);

        __builtin_amdgcn_s_setprio(1);
        #pragma unroll
        for (int mi = 0; mi < 4; ++mi)
            #pragma unroll
            for (int ni = 0; ni < 4; ++ni)
                acc[mi][ni] = __builtin_amdgcn_mfma_f32_16x16x32_bf16(
                    af[mi], bfr[ni], acc[mi][ni], 0, 0, 0);
        __builtin_amdgcn_s_setprio(0);
    }

    const int emode = isQ ? 1 : (((n0 + wn) < 512) ? 2 : 0);
    if (emode) {
        const float* gamma = (emode == 1) ? qg : kg;
        const float post = (emode == 1) ? (0.125f * 1.44269504088896f) : 1.0f;
        float g4[4];
        #pragma unroll
        for (int ni = 0; ni < 4; ++ni) g4[ni] = gamma[ni * 16 + lr];

        #pragma unroll
        for (int mi = 0; mi < 4; ++mi)
            #pragma unroll
            for (int r = 0; r < 4; ++r) {
                const int m = m0 + wm + mi * 16 + lg * 4 + r;
                float ss = 0.0f;
                #pragma unroll
                for (int ni = 0; ni < 4; ++ni) ss += acc[mi][ni][r] * acc[mi][ni][r];
                ss += __shfl_xor(ss, 1);
                ss += __shfl_xor(ss, 2);
                ss += __shfl_xor(ss, 4);
                ss += __shfl_xor(ss, 8);
                const float rn = rsqrtf(ss * (1.0f / 64.0f) + 1e-6f);
                int bb, pos;
                if (emode == 1) { bb = m >> 10; pos = 1024 + (m & 1023); }
                else            { bb = m >> 11; pos = m & 2047; }
                const float* cp = cosb + (((size_t)bb * 2048 + pos) << 6);
                const float* sp = sinb + (((size_t)bb * 2048 + pos) << 6);
                float qn[4];
                #pragma unroll
                for (int ni = 0; ni < 4; ++ni) qn[ni] = acc[mi][ni][r] * rn * g4[ni];
                #pragma unroll
                for (int ni = 0; ni < 4; ++ni) {
                    const float rot = (ni < 2) ? -qn[ni + 2] : qn[ni - 2];
                    acc[mi][ni][r] = (qn[ni] * cp[ni * 16 + lr] + rot * sp[ni * 16 + lr]) * post;
                }
            }
    }

    #pragma unroll
    for (int mi = 0; mi < 4; ++mi)
        #pragma unroll
        for (int r = 0; r < 4; ++r) {
            const int m = m0 + wm + mi * 16 + lg * 4 + r;
            bf16_t* crow = C + (size_t)m * NN + n0 + wn + lr;
            crow[0]  = (bf16_t)acc[mi][0][r];
            crow[16] = (bf16_t)acc[mi][1][r];
            crow[32] = (bf16_t)acc[mi][2][r];
            crow[48] = (bf16_t)acc[mi][3][r];
        }
}

// ---------------------------------------------------------------------------
// Out-projection GEMM v2: C[m,n] = sum_k A[m,k]*B[n,k], fp32 C.
// ---------------------------------------------------------------------------
__global__ __launch_bounds__(256)
void gemm_out2(const bf16_t* __restrict__ A, const bf16_t* __restrict__ Bw,
               float* __restrict__ C)
{
    __shared__ __align__(16) bf16_t Ads[3][2048];   // [64][32] x3
    __shared__ __align__(16) bf16_t Bds[3][4096];   // [128][32] x3

    const int tid  = threadIdx.x;
    const int wave = tid >> 6;
    const int lane = tid & 63;

    const int bid = blockIdx.x;
    const int swz = (bid & 7) * 64 + (bid >> 3);
    const int m0 = (swz & 31) << 6;
    const int n0 = (swz >> 5) << 7;

    const int wm = (wave >> 1) << 5;
    const int wn = (wave & 1) << 6;
    const int lr = lane & 15;
    const int lg = lane >> 4;

    const int sr = lane >> 2;
    const int sc = (lane & 3) << 3;

    const size_t aoff  = (size_t)(m0 + wave * 16 + sr) * HID + sc;
    size_t boff[2];
    #pragma unroll
    for (int cc = 0; cc < 2; ++cc)
        boff[cc] = (size_t)(n0 + wave * 32 + cc * 16 + sr) * HID + sc;

    f32x4 acc[2][4];
    #pragma unroll
    for (int i = 0; i < 2; ++i)
        #pragma unroll
        for (int j = 0; j < 4; ++j)
            #pragma unroll
            for (int r = 0; r < 4; ++r) acc[i][j][r] = 0.0f;

    auto STAGE = [&](int buf, int k0) {
        gload16(A + aoff + k0, &Ads[buf][wave << 9]);
        #pragma unroll
        for (int cc = 0; cc < 2; ++cc)
            gload16(Bw + boff[cc] + k0, &Bds[buf][(wave * 2 + cc) << 9]);
    };

    constexpr int nk = HID / 32;   // 64
    STAGE(0, 0);
    STAGE(1, 32);

    for (int t = 0; t < nk; ++t) {
        if (t < nk - 1) asm volatile("s_waitcnt vmcnt(3)" ::: "memory");
        else            asm volatile("s_waitcnt vmcnt(0)" ::: "memory");
        __builtin_amdgcn_s_barrier();
        __builtin_amdgcn_sched_barrier(0);

        const int buf = t % 3;
        bf16x8 af[2], bfr[4];
        #pragma unroll
        for (int i = 0; i < 2; ++i)
            af[i]  = *reinterpret_cast<const bf16x8*>(&Ads[buf][(wm + i * 16 + lr) * 32 + lg * 8]);
        #pragma unroll
        for (int i = 0; i < 4; ++i)
            bfr[i] = *reinterpret_cast<const bf16x8*>(&Bds[buf][(wn + i * 16 + lr) * 32 + lg * 8]);
        asm volatile("s_waitcnt lgkmcnt(0)" ::: "memory");
        __builtin_amdgcn_sched_barrier(0);

        if (t + 2 < nk) STAGE((t + 2) % 3, (t + 2) * 32);

        __builtin_amdgcn_s_setprio(1);
        #pragma unroll
        for (int mi = 0; mi < 2; ++mi)
            #pragma unroll
            for (int ni = 0; ni < 4; ++ni)
                acc[mi][ni] = __builtin_amdgcn_mfma_f32_16x16x32_bf16(
                    af[mi], bfr[ni], acc[mi][ni], 0, 0, 0);
        __builtin_amdgcn_s_setprio(0);
    }

    #pragma unroll
    for (int mi = 0; mi < 2; ++mi)
        #pragma unroll
        for (int r = 0; r < 4; ++r) {
            const int m = m0 + wm + mi * 16 + lg * 4 + r;
            float* crow = C + (size_t)m * 2048 + n0 + wn + lr;
            crow[0]  = acc[mi][0][r];
            crow[16] = acc[mi][1][r];
            crow[32] = acc[mi][2][r];
            crow[48] = acc[mi][3][r];
        }
}

// ---------------------------------------------------------------------------
// bf16 MFMA flash attention (r12 version VERBATIM -- best measured: 71.0us).
// 8 waves (512 thr), QBLK=128 (wave owns 16 q-rows), KV tile 64,
// double-buffered K/V with register prefetch, ONE barrier per tile.
// Softmax: bare exp2 (Q pre-scaled by 0.125*log2e; 2^bias cancels in ratio).
// PV + l: mfma_f32_16x16x16bf16_1k with P as the A-operand (QK^T C-layout ==
// 16x16x16 A-frag layout, zero exchange). V consumed as b64 B-frags from the
// [d][t] layout. WITH s_setprio around both MFMA clusters: r15 A/B measured
// removing it costs +6us (71->77) -- this loop has per-phase wave role
// diversity (prefetch vs MFMA), the T5-enabling condition.
// History: no-setprio (r15, 77us), static-unroll (r13, 74us), KVBLK=128
// (r14, 93us), 4-wave/32q (r11, 86us), split-T (r9, 82us) all regressed.
// Grid: (B*NH, Sq/128). Output bf16 in place over Q.
// ---------------------------------------------------------------------------
__global__ __launch_bounds__(512)
void flash_mfma(const bf16_t* __restrict__ Qb, const bf16_t* __restrict__ KVb,
                bf16_t* __restrict__ Ob)
{
    const int bh = blockIdx.x;
    const int b  = bh >> 5;
    const int h  = bh & 31;
    const int g  = h >> 2;
    const int q0 = blockIdx.y << 7;
    const int tid  = threadIdx.x;
    const int wave = tid >> 6;
    const int lane = tid & 63;
    const int lr = lane & 15;
    const int lg = lane >> 4;

    __shared__ __align__(16) bf16_t Kd[2][64][68];      // [k][d]
    __shared__ __align__(16) bf16_t Vd[2][64][68];      // [d][t]

    // staging assignment (block-wide, 512 threads)
    const int kr = tid >> 3;            // K row 0..63
    const int kc = (tid & 7) << 3;      // K col 0,8,..,56
    const int tp = tid >> 4;            // V t-pair 0..31
    const int d0 = (tid & 15) << 2;     // V d-group

    const size_t kbase = (size_t)(b * Tt) * 1024 + g * 64;

    // Q fragments (B-operand of S^T = K*Q^T); Q pre-scaled by Cs.
    bf16x8 qf[2];
    {
        const bf16_t* qp = Qb + (size_t)(b * Sq + q0 + wave * 16 + lr) * 2048 + h * 64 + lg * 8;
        qf[0] = *reinterpret_cast<const bf16x8*>(qp);
        qf[1] = *reinterpret_cast<const bf16x8*>(qp + 32);
    }

    // ones B-fragment (bf16 1.0) for the l row-sum MFMA
    s16x4 onesB;
    #pragma unroll
    for (int j = 0; j < 4; ++j) onesB[j] = (short)0x3F80;

    f32x4 lacc;
    #pragma unroll
    for (int j = 0; j < 4; ++j) lacc[j] = 0.0f;
    f32x4 oacc[4];
    #pragma unroll
    for (int dt = 0; dt < 4; ++dt)
        #pragma unroll
        for (int j = 0; j < 4; ++j) oacc[dt][j] = 0.0f;

    // prologue: load tile 0 into regs, write buf 0
    bf16x8 kreg;
    bf16x4 vr0, vr1;
    {
        kreg = *reinterpret_cast<const bf16x8*>(KVb + kbase + (size_t)kr * 1024 + kc);
        const bf16_t* vp = KVb + kbase + (size_t)(tp * 2) * 1024 + 512 + d0;
        vr0 = *reinterpret_cast<const bf16x4*>(vp);
        vr1 = *reinterpret_cast<const bf16x4*>(vp + 1024);
    }
    *reinterpret_cast<bf16x8*>(&Kd[0][kr][kc]) = kreg;
    #pragma unroll
    for (int j = 0; j < 4; ++j) {
        bf16x2 w; w[0] = vr0[j]; w[1] = vr1[j];
        *reinterpret_cast<bf16x2*>(&Vd[0][d0 + j][tp * 2]) = w;
    }
    __syncthreads();

    int cur = 0;

    for (int t0 = 0; t0 < Tt; t0 += 64) {
        const bool more = (t0 + 64 < Tt);
        if (more) {
            const size_t tb = kbase + (size_t)(t0 + 64) * 1024;
            kreg = *reinterpret_cast<const bf16x8*>(KVb + tb + (size_t)kr * 1024 + kc);
            const bf16_t* vp = KVb + tb + (size_t)(tp * 2) * 1024 + 512 + d0;
            vr0 = *reinterpret_cast<const bf16x4*>(vp);
            vr1 = *reinterpret_cast<const bf16x4*>(vp + 1024);
        }

        // QK^T (swapped): S^T = K * Q^T (already in log2 units)
        f32x4 sc[4];
        __builtin_amdgcn_s_setprio(1);
        #pragma unroll
        for (int kt = 0; kt < 4; ++kt) {
            f32x4 z;
            #pragma unroll
            for (int j = 0; j < 4; ++j) z[j] = 0.0f;
            const bf16x8 kf0 = *reinterpret_cast<const bf16x8*>(&Kd[cur][kt * 16 + lr][lg * 8]);
            const bf16x8 kf1 = *reinterpret_cast<const bf16x8*>(&Kd[cur][kt * 16 + lr][32 + lg * 8]);
            z = __builtin_amdgcn_mfma_f32_16x16x32_bf16(kf0, qf[0], z, 0, 0, 0);
            z = __builtin_amdgcn_mfma_f32_16x16x32_bf16(kf1, qf[1], z, 0, 0, 0);
            sc[kt] = z;
        }
        __builtin_amdgcn_s_setprio(0);

        // bare-exp2 softmax -> bf16 P packed directly as 16x16x16 A-frags
        s16x4 pa[4];
        #pragma unroll
        for (int kt = 0; kt < 4; ++kt) {
            bf16x4 pw;
            #pragma unroll
            for (int j = 0; j < 4; ++j) pw[j] = (bf16_t)exp2f(sc[kt][j]);
            pa[kt] = *reinterpret_cast<s16x4*>(&pw);
        }

        // PV: O = P * V via 16x16x16 (P is the A-operand, zero exchange);
        // V B-frags read b64 from the [d][t] layout.
        __builtin_amdgcn_s_setprio(1);
        #pragma unroll
        for (int dt = 0; dt < 4; ++dt)
            #pragma unroll
            for (int kt = 0; kt < 4; ++kt) {
                const s16x4 vf = *reinterpret_cast<const s16x4*>(
                    &Vd[cur][dt * 16 + lr][kt * 16 + lg * 4]);
                oacc[dt] = __builtin_amdgcn_mfma_f32_16x16x16bf16_1k(
                    pa[kt], vf, oacc[dt], 0, 0, 0);
            }
        // l row-sum on the matrix pipe (B = ones)
        #pragma unroll
        for (int kt = 0; kt < 4; ++kt)
            lacc = __builtin_amdgcn_mfma_f32_16x16x16bf16_1k(pa[kt], onesB, lacc, 0, 0, 0);
        __builtin_amdgcn_s_setprio(0);

        // stage next tile into the other buffer; single barrier per tile
        if (more) {
            *reinterpret_cast<bf16x8*>(&Kd[cur ^ 1][kr][kc]) = kreg;
            #pragma unroll
            for (int j = 0; j < 4; ++j) {
                bf16x2 w; w[0] = vr0[j]; w[1] = vr1[j];
                *reinterpret_cast<bf16x2*>(&Vd[cur ^ 1][d0 + j][tp * 2]) = w;
            }
            __syncthreads();
        }
        cur ^= 1;
    }

    // finalize: lane holds O[q = lg*4+r][d = dt*16+lr], l[q] = lacc[r];
    // write bf16 in place over Q.
    f32x4 inv4;
    #pragma unroll
    for (int r = 0; r < 4; ++r) inv4[r] = 1.0f / lacc[r];
    #pragma unroll
    for (int r = 0; r < 4; ++r) {
        bf16_t* orow = Ob + (size_t)(b * Sq + q0 + wave * 16 + lg * 4 + r) * 2048 + h * 64 + lr;
        #pragma unroll
        for (int dt = 0; dt < 4; ++dt)
            orow[dt * 16] = (bf16_t)(oacc[dt][r] * inv4[r]);
    }
}

// ---------------------------------------------------------------------------
extern "C" void kernel_launch(void* const* d_in, const int* in_sizes, int n_in,
                              void* d_out, int out_size, void* d_ws, size_t ws_size,
                              hipStream_t stream)
{
    const float* hs   = (const float*)d_in[0];
    const float* tctx = (const float*)d_in[1];
    const float* cosb = (const float*)d_in[2];
    const float* sinb = (const float*)d_in[3];
    const float* Wq   = (const float*)d_in[4];
    const float* Wk   = (const float*)d_in[5];
    const float* Wv   = (const float*)d_in[6];
    const float* Wo   = (const float*)d_in[7];
    const float* qg   = (const float*)d_in[8];
    const float* kg   = (const float*)d_in[9];
    float* out = (float*)d_out;

    // workspace layout (bf16 elems): total 23,068,672 elems = 46.1 MB
    bf16_t* W     = (bf16_t*)d_ws;
    bf16_t* kvinb = W;                    // [B][2048][2048] concat: 8,388,608
    bf16_t* Wqb   = kvinb + 8388608;      // Wq (4,194,304) + Wkv (2,097,152)
    bf16_t* Qb    = Wqb + 6291456;        // q / attn in-place: 4,194,304
    bf16_t* KVb   = Qb + 4194304;         // k|v: 4,194,304
    bf16_t* Wob   = kvinb;                // reused after gemm_qkv2 consumes kvinb

    // fused converts: concat + all three projection weights (one launch)
    cvt_all<<<7168, 256, 0, stream>>>(tctx, hs, Wq, Wk, Wv, kvinb);

    // fused Q + KV projections with RMSNorm/RoPE(+Cs on Q) epilogue
    gemm_qkv2<<<512, 256, 0, stream>>>(kvinb, Wqb, Qb, KVb, qg, kg, cosb, sinb);

    // convert Wo into kvinb's space
    cvt_bf16<<<2048, 256, 0, stream>>>(Wo, Wob, 4194304);

    // flash attention (bf16 MFMA), bf16 output in place over Q
    flash_mfma<<<dim3(Bc * NH, Sq / 128), 512, 0, stream>>>(Qb, KVb, Qb);

    // output projection: attn(bf16) @ Wo^T -> fp32 out
    gemm_out2<<<512, 256, 0, stream>>>(Qb, Wob, out);
}